// Round 7
// baseline (135.486 us; speedup 1.0000x reference)
//
#include <hip/hip_runtime.h>
#include <cstdint>

#define N_RNA 4000
#define N_DIS 2000
#define NNODE 6016
#define NFDIM 128
#define RDIM 64
#define NE 300000
#define NET (NE + NNODE)
#define NPAIR 500000
#define NTILE (NPAIR / 16)  // 31250 exactly

typedef float vf4 __attribute__((ext_vector_type(4)));
typedef _Float16 f16x8 __attribute__((ext_vector_type(8)));
typedef _Float16 f16x2 __attribute__((ext_vector_type(2)));

union FragU {
    f16x8 f;
    f16x2 h[4];
    int   u[4];
};

__device__ __forceinline__ f16x2 pkrtz(float lo, float hi) {
    auto r = __builtin_amdgcn_cvt_pkrtz(lo, hi);
    return __builtin_bit_cast(f16x2, r);
}
__device__ __forceinline__ vf4 mfma16(const FragU& a, const FragU& b, vf4 c) {
    return __builtin_amdgcn_mfma_f32_16x16x32_f16(a.f, b.f, c, 0, 0, 0);
}

// Rebuild B-fragment (next layer's a^T) from two C/D acc tiles, in-register.
__device__ __forceinline__ FragU trans32(vf4 a0, vf4 a1, int col, int g) {
    FragU w;
    w.h[0] = pkrtz(a0[0], a0[1]);
    w.h[1] = pkrtz(a0[2], a0[3]);
    w.h[2] = pkrtz(a1[0], a1[1]);
    w.h[3] = pkrtz(a1[2], a1[3]);
    int addrA = (col + 16 * ((2 * g) & 3)) * 4;
    int addrB = (col + 16 * ((2 * g + 1) & 3)) * 4;
    int t0a = __builtin_amdgcn_ds_bpermute(addrA, w.u[0]);
    int t1a = __builtin_amdgcn_ds_bpermute(addrA, w.u[1]);
    int t2a = __builtin_amdgcn_ds_bpermute(addrA, w.u[2]);
    int t3a = __builtin_amdgcn_ds_bpermute(addrA, w.u[3]);
    int t0b = __builtin_amdgcn_ds_bpermute(addrB, w.u[0]);
    int t1b = __builtin_amdgcn_ds_bpermute(addrB, w.u[1]);
    int t2b = __builtin_amdgcn_ds_bpermute(addrB, w.u[2]);
    int t3b = __builtin_amdgcn_ds_bpermute(addrB, w.u[3]);
    bool hi = g >= 2;
    FragU B;
    B.u[0] = hi ? t2a : t0a;
    B.u[1] = hi ? t3a : t1a;
    B.u[2] = hi ? t2b : t0b;
    B.u[3] = hi ? t3b : t1b;
    return B;
}

// 16-feature source (single acc tile) -> K=32 fragment zero-padded for k>=16.
__device__ __forceinline__ FragU trans16(vf4 a, int col, int g) {
    int w0, w1;
    {
        f16x2 p0 = pkrtz(a[0], a[1]);
        f16x2 p1 = pkrtz(a[2], a[3]);
        FragU tmp; tmp.h[0] = p0; tmp.h[1] = p1;
        w0 = tmp.u[0]; w1 = tmp.u[1];
    }
    int addrA = (col + 16 * ((2 * g) & 3)) * 4;
    int addrB = (col + 16 * ((2 * g + 1) & 3)) * 4;
    int j0 = __builtin_amdgcn_ds_bpermute(addrA, w0);
    int j1 = __builtin_amdgcn_ds_bpermute(addrA, w1);
    int j2 = __builtin_amdgcn_ds_bpermute(addrB, w0);
    int j3 = __builtin_amdgcn_ds_bpermute(addrB, w1);
    bool lo2 = g < 2;
    FragU B;
    B.u[0] = lo2 ? j0 : 0;
    B.u[1] = lo2 ? j1 : 0;
    B.u[2] = lo2 ? j2 : 0;
    B.u[3] = lo2 ? j3 : 0;
    return B;
}

// ---------------- CSR build ----------------
__global__ void init_cnt(int* __restrict__ cnt, int* __restrict__ cur) {
    int i = blockIdx.x * blockDim.x + threadIdx.x;
    if (i < NNODE) { cnt[i] = 0; cur[i] = 0; }
}

__global__ void count_edges(const int* __restrict__ adj, int* __restrict__ cnt) {
    int k = blockIdx.x * blockDim.x + threadIdx.x;
    if (k >= NET) return;
    int dst = (k < NE) ? adj[NE + k] : (k - NE);
    atomicAdd(&cnt[dst], 1);
}

__global__ __launch_bounds__(256) void scan_counts(const int* __restrict__ cnt,
                                                   int* __restrict__ offs) {
    __shared__ int part[256];
    const int C = 24;  // 256*24 = 6144 >= 6016
    int t = threadIdx.x;
    int base = t * C;
    int loc[C];
    int sum = 0;
#pragma unroll
    for (int i = 0; i < C; i++) {
        int idx = base + i;
        int v = (idx < NNODE) ? cnt[idx] : 0;
        loc[i] = sum;
        sum += v;
    }
    part[t] = sum;
    __syncthreads();
    for (int off = 1; off < 256; off <<= 1) {
        int v = (t >= off) ? part[t - off] : 0;
        __syncthreads();
        part[t] += v;
        __syncthreads();
    }
    int ebase = part[t] - sum;
#pragma unroll
    for (int i = 0; i < C; i++) {
        int idx = base + i;
        if (idx < NNODE) offs[idx] = ebase + loc[i];
    }
    if (t == 255) offs[NNODE] = part[255];
}

__global__ void fill_csr(const int* __restrict__ adj, const int* __restrict__ offs,
                         int* __restrict__ cur, int* __restrict__ srcs) {
    int k = blockIdx.x * blockDim.x + threadIdx.x;
    if (k >= NET) return;
    int src, dst;
    if (k < NE) { src = adj[k]; dst = adj[NE + k]; }
    else        { src = k - NE; dst = k - NE; }
    int pos = atomicAdd(&cur[dst], 1);
    srcs[offs[dst] + pos] = src;
}

// ---------------- GAT projection: 4 nodes per wave, W loaded once per 4 ----------------
template <int NF>
__global__ __launch_bounds__(64) void proj_kernel(const float* __restrict__ x,
                                                  const float* __restrict__ W,
                                                  const float* __restrict__ a_s,
                                                  const float* __restrict__ a_d,
                                                  float* __restrict__ h,
                                                  float* __restrict__ ssrc,
                                                  float* __restrict__ sdst) {
    __shared__ float xr[4][NF];
    int nb = blockIdx.x * 4;
    int t = threadIdx.x;
    for (int idx = t; idx < 4 * NF; idx += 64)
        xr[idx / NF][idx % NF] = x[(size_t)nb * NF + idx];
    __syncthreads();
    float a0 = 0.f, a1 = 0.f, a2 = 0.f, a3 = 0.f;
#pragma unroll 8
    for (int k = 0; k < NF; k++) {
        float wv = W[k * RDIM + t];
        a0 = fmaf(xr[0][k], wv, a0);
        a1 = fmaf(xr[1][k], wv, a1);
        a2 = fmaf(xr[2][k], wv, a2);
        a3 = fmaf(xr[3][k], wv, a3);
    }
    h[(size_t)(nb + 0) * RDIM + t] = a0;
    h[(size_t)(nb + 1) * RDIM + t] = a1;
    h[(size_t)(nb + 2) * RDIM + t] = a2;
    h[(size_t)(nb + 3) * RDIM + t] = a3;
    float asv = a_s[t], adv = a_d[t];
    float acc[4] = {a0, a1, a2, a3};
#pragma unroll
    for (int i = 0; i < 4; i++) {
        float vs = acc[i] * asv;
        float vd = acc[i] * adv;
#pragma unroll
        for (int off = 32; off; off >>= 1) {
            vs += __shfl_down(vs, off);
            vd += __shfl_down(vd, off);
        }
        if (t == 0) { ssrc[nb + i] = vs; sdst[nb + i] = vd; }
    }
}

// ---------------- GAT aggregation v2: 4 edge-groups x 16 lanes x float4 ----------------
__global__ __launch_bounds__(64) void agg_kernel(const float* __restrict__ h,
                                                 const float* __restrict__ ssrc,
                                                 const float* __restrict__ sdst,
                                                 const int* __restrict__ offs,
                                                 const int* __restrict__ srcs,
                                                 const float* __restrict__ bias,
                                                 float* __restrict__ out) {
    int node = blockIdx.x;
    int t = threadIdx.x;
    int beg = offs[node], end = offs[node + 1];
    float sd = sdst[node];
    // pass 1: segment max, 64 lanes over edges
    float m = -1e30f;
    for (int i = beg + t; i < end; i += 64) {
        float v = ssrc[srcs[i]] + sd;
        v = v > 0.f ? v : 0.2f * v;
        m = fmaxf(m, v);
    }
#pragma unroll
    for (int off = 32; off; off >>= 1) m = fmaxf(m, __shfl_xor(m, off));
    // pass 2: 4 edges in parallel; 16 lanes x float4 cover the 64 features
    int g = t >> 4, q = t & 15;
    float ax = 0.f, ay = 0.f, az = 0.f, aw = 0.f, den = 0.f;
    for (int i = beg + g; i < end; i += 4) {
        int s = srcs[i];
        float v = ssrc[s] + sd;
        v = v > 0.f ? v : 0.2f * v;
        float ex = __expf(v - m);
        den += ex;
        float4 hv = *(const float4*)(h + (size_t)s * 64 + q * 4);
        ax = fmaf(ex, hv.x, ax);
        ay = fmaf(ex, hv.y, ay);
        az = fmaf(ex, hv.z, az);
        aw = fmaf(ex, hv.w, aw);
    }
#pragma unroll
    for (int off = 16; off <= 32; off <<= 1) {
        ax += __shfl_xor(ax, off);
        ay += __shfl_xor(ay, off);
        az += __shfl_xor(az, off);
        aw += __shfl_xor(aw, off);
        den += __shfl_xor(den, off);
    }
    if (t < 16) {
        float inv = 1.f / den;
        float4 b4 = ((const float4*)bias)[q];
        float4 o;
        o.x = ax * inv + b4.x;
        o.y = ay * inv + b4.y;
        o.z = az * inv + b4.z;
        o.w = aw * inv + b4.w;
        *(float4*)(out + (size_t)node * 64 + q * 4) = o;
    }
}

// ---------------- pair-independent layer-1 precompute: 4 nodes per wave ----------------
__global__ __launch_bounds__(64) void pair_pre_kernel(const float* __restrict__ h,
                                                      const float* __restrict__ w1,
                                                      const float* __restrict__ b1,
                                                      float* __restrict__ u1,
                                                      float* __restrict__ u2) {
    __shared__ float xr[4][64];
    int nb = blockIdx.x * 4;   // N_RNA=4000 divisible by 4: block never straddles types
    int t = threadIdx.x;
    for (int idx = t; idx < 256; idx += 64)
        xr[idx >> 6][idx & 63] = h[(size_t)nb * RDIM + idx];
    __syncthreads();
    bool rna = nb < N_RNA;
    const float* w = rna ? w1 : (w1 + 64 * 64);
    float bv = rna ? b1[t] : 0.f;
    float a0 = bv, a1 = bv, a2 = bv, a3 = bv;
#pragma unroll 8
    for (int k = 0; k < 64; k++) {
        float wv = w[k * 64 + t];
        a0 = fmaf(xr[0][k], wv, a0);
        a1 = fmaf(xr[1][k], wv, a1);
        a2 = fmaf(xr[2][k], wv, a2);
        a3 = fmaf(xr[3][k], wv, a3);
    }
    if (rna) {
        u1[(size_t)(nb + 0) * 64 + t] = a0;
        u1[(size_t)(nb + 1) * 64 + t] = a1;
        u1[(size_t)(nb + 2) * 64 + t] = a2;
        u1[(size_t)(nb + 3) * 64 + t] = a3;
    } else {
        int db = nb - N_RNA;
        u2[(size_t)(db + 0) * 64 + t] = a0;
        u2[(size_t)(db + 1) * 64 + t] = a1;
        u2[(size_t)(db + 2) * 64 + t] = a2;
        u2[(size_t)(db + 3) * 64 + t] = a3;
    }
}

// ---------------- pairwise MLP: f16 MFMA transposed chain ----------------
__global__ __launch_bounds__(256) void mlp_mfma_kernel(
    const float* __restrict__ u1, const float* __restrict__ u2,
    const int* __restrict__ coo,
    const float* __restrict__ w2, const float* __restrict__ b2,
    const float* __restrict__ w3, const float* __restrict__ b3,
    const float* __restrict__ w4, const float* __restrict__ b4,
    const float* __restrict__ w5, const float* __restrict__ b5,
    const float* __restrict__ w6, const float* __restrict__ b6,
    float* __restrict__ out) {
    const int lane = threadIdx.x & 63;
    const int col  = lane & 15;   // pair-in-tile (B/D col)
    const int g    = lane >> 4;   // k-group
    const int wid  = blockIdx.x * 4 + (threadIdx.x >> 6);
    const int nwaves = gridDim.x * 4;

    // ---- loop-invariant A-operands: transposed weights as f16 fragments ----
    FragU A2[2][2];  // [t out-tile][kt k-tile], w2: [64][32]
#pragma unroll
    for (int t = 0; t < 2; t++)
#pragma unroll
        for (int kt = 0; kt < 2; kt++)
#pragma unroll
            for (int j = 0; j < 4; j++) {
                int k = kt * 32 + g * 8 + 2 * j;
                A2[t][kt].h[j] = pkrtz(w2[k * 32 + t * 16 + col],
                                       w2[(k + 1) * 32 + t * 16 + col]);
            }
    FragU A3[2];  // w3: [32][32]
#pragma unroll
    for (int t = 0; t < 2; t++)
#pragma unroll
        for (int j = 0; j < 4; j++) {
            int k = g * 8 + 2 * j;
            A3[t].h[j] = pkrtz(w3[k * 32 + t * 16 + col],
                               w3[(k + 1) * 32 + t * 16 + col]);
        }
    FragU A4;  // w4: [32][16]
#pragma unroll
    for (int j = 0; j < 4; j++) {
        int k = g * 8 + 2 * j;
        A4.h[j] = pkrtz(w4[k * 16 + col], w4[(k + 1) * 16 + col]);
    }
    FragU A5;  // w5: [16][8]; rows(out)>=8 and k>=16 zero-padded
#pragma unroll
    for (int j = 0; j < 4; j++) {
        int k = g * 8 + 2 * j;
        if (g < 2 && col < 8)
            A5.h[j] = pkrtz(w5[k * 8 + col], w5[(k + 1) * 8 + col]);
        else
            A5.u[j] = 0;
    }
    // ---- biases per lane: out-feature = t*16 + 4g + r ----
    float bias2[8], bias3[8], bias4[4], bias5[4], w6r[4];
#pragma unroll
    for (int t = 0; t < 2; t++)
#pragma unroll
        for (int r = 0; r < 4; r++) {
            bias2[t * 4 + r] = b2[t * 16 + g * 4 + r];
            bias3[t * 4 + r] = b3[t * 16 + g * 4 + r];
        }
#pragma unroll
    for (int r = 0; r < 4; r++) {
        bias4[r] = b4[g * 4 + r];
        bias5[r] = (g < 2) ? b5[g * 4 + r] : 0.f;
        w6r[r]   = (g < 2) ? w6[g * 4 + r] : 0.f;
    }
    float b6v = b6[0];
    const vf4 z = {0.f, 0.f, 0.f, 0.f};

    for (int tile = wid; tile < NTILE; tile += nwaves) {
        int p = tile * 16 + col;
        int2 rd = ((const int2*)coo)[p];
        const float4* pr = (const float4*)(u1 + (size_t)rd.x * 64);
        const float4* pd = (const float4*)(u2 + (size_t)rd.y * 64);
        // entry: B = a1^T fragments, features g*8..g*8+7 (+32 for kt=1)
        FragU B0, B1;
        {
            float4 a = pr[2 * g],     b = pd[2 * g];
            float4 c = pr[2 * g + 1], d = pd[2 * g + 1];
            B0.h[0] = pkrtz(fmaxf(a.x + b.x, 0.f), fmaxf(a.y + b.y, 0.f));
            B0.h[1] = pkrtz(fmaxf(a.z + b.z, 0.f), fmaxf(a.w + b.w, 0.f));
            B0.h[2] = pkrtz(fmaxf(c.x + d.x, 0.f), fmaxf(c.y + d.y, 0.f));
            B0.h[3] = pkrtz(fmaxf(c.z + d.z, 0.f), fmaxf(c.w + d.w, 0.f));
            a = pr[8 + 2 * g];     b = pd[8 + 2 * g];
            c = pr[8 + 2 * g + 1]; d = pd[8 + 2 * g + 1];
            B1.h[0] = pkrtz(fmaxf(a.x + b.x, 0.f), fmaxf(a.y + b.y, 0.f));
            B1.h[1] = pkrtz(fmaxf(a.z + b.z, 0.f), fmaxf(a.w + b.w, 0.f));
            B1.h[2] = pkrtz(fmaxf(c.x + d.x, 0.f), fmaxf(c.y + d.y, 0.f));
            B1.h[3] = pkrtz(fmaxf(c.z + d.z, 0.f), fmaxf(c.w + d.w, 0.f));
        }
        // layer 2 (64 -> 32): 2 out-tiles x 2 k-tiles
        vf4 acc0 = mfma16(A2[0][0], B0, z);
        acc0 = mfma16(A2[0][1], B1, acc0);
        vf4 acc1 = mfma16(A2[1][0], B0, z);
        acc1 = mfma16(A2[1][1], B1, acc1);
#pragma unroll
        for (int r = 0; r < 4; r++) {
            acc0[r] = fmaxf(acc0[r] + bias2[r], 0.f);
            acc1[r] = fmaxf(acc1[r] + bias2[4 + r], 0.f);
        }
        // layer 3 (32 -> 32)
        FragU Bx = trans32(acc0, acc1, col, g);
        acc0 = mfma16(A3[0], Bx, z);
        acc1 = mfma16(A3[1], Bx, z);
#pragma unroll
        for (int r = 0; r < 4; r++) {
            acc0[r] = fmaxf(acc0[r] + bias3[r], 0.f);
            acc1[r] = fmaxf(acc1[r] + bias3[4 + r], 0.f);
        }
        // layer 4 (32 -> 16)
        Bx = trans32(acc0, acc1, col, g);
        vf4 a4 = mfma16(A4, Bx, z);
#pragma unroll
        for (int r = 0; r < 4; r++) a4[r] = fmaxf(a4[r] + bias4[r], 0.f);
        // layer 5 (16 -> 8, padded to 16x32)
        Bx = trans16(a4, col, g);
        vf4 a5 = mfma16(A5, Bx, z);
        // layer 6 (8 -> 1) + sigmoid on VALU
        float part = 0.f;
#pragma unroll
        for (int r = 0; r < 4; r++)
            part = fmaf(fmaxf(a5[r] + bias5[r], 0.f), w6r[r], part);
        part += __shfl_xor(part, 16);
        float sig = 1.f / (1.f + __expf(-(part + b6v)));
        if (g == 0) out[tile * 16 + col] = sig;
    }
}

// ---------------- launch ----------------
extern "C" void kernel_launch(void* const* d_in, const int* in_sizes, int n_in,
                              void* d_out, int out_size, void* d_ws, size_t ws_size,
                              hipStream_t stream) {
    const float* x    = (const float*)d_in[0];
    const int*   adj  = (const int*)d_in[1];
    const int*   coo  = (const int*)d_in[2];
    const float* gw0  = (const float*)d_in[3];
    const float* gas0 = (const float*)d_in[4];
    const float* gad0 = (const float*)d_in[5];
    const float* gb0  = (const float*)d_in[6];
    const float* gw1  = (const float*)d_in[7];
    const float* gas1 = (const float*)d_in[8];
    const float* gad1 = (const float*)d_in[9];
    const float* gb1  = (const float*)d_in[10];

    char* ws = (char*)d_ws;
    size_t o = 0;
    auto take = [&](size_t bytes) -> void* {
        void* p = ws + o;
        o = (o + bytes + 255) & ~(size_t)255;
        return p;
    };
    float* hP   = (float*)take((size_t)NNODE * RDIM * 4);
    float* hO1  = (float*)take((size_t)NNODE * RDIM * 4);
    float* hO2  = (float*)take((size_t)NNODE * RDIM * 4);
    float* u1   = (float*)take((size_t)N_RNA * 64 * 4);
    float* u2   = (float*)take((size_t)N_DIS * 64 * 4);
    float* ssrc = (float*)take((size_t)NNODE * 4);
    float* sdst = (float*)take((size_t)NNODE * 4);
    int*   offs = (int*)take((size_t)(NNODE + 1) * 4);
    int*   cnt  = (int*)take((size_t)NNODE * 4);
    int*   cur  = (int*)take((size_t)NNODE * 4);
    int*   srcs = (int*)take((size_t)NET * 4);

    init_cnt<<<(NNODE + 255) / 256, 256, 0, stream>>>(cnt, cur);
    count_edges<<<(NET + 255) / 256, 256, 0, stream>>>(adj, cnt);
    scan_counts<<<1, 256, 0, stream>>>(cnt, offs);
    fill_csr<<<(NET + 255) / 256, 256, 0, stream>>>(adj, offs, cur, srcs);

    // GAT layer 1 (proj: 4 nodes/wave)
    proj_kernel<NFDIM><<<NNODE / 4, 64, 0, stream>>>(x, gw0, gas0, gad0, hP, ssrc, sdst);
    agg_kernel<<<NNODE, 64, 0, stream>>>(hP, ssrc, sdst, offs, srcs, gb0, hO1);
    // GAT layer 2
    proj_kernel<RDIM><<<NNODE / 4, 64, 0, stream>>>(hO1, gw1, gas1, gad1, hP, ssrc, sdst);
    agg_kernel<<<NNODE, 64, 0, stream>>>(hP, ssrc, sdst, offs, srcs, gb1, hO2);

    // layer-1 precompute: u1 (rna nodes, +b1 folded), u2 (dis nodes)
    pair_pre_kernel<<<(N_RNA + N_DIS) / 4, 64, 0, stream>>>(
        hO2, (const float*)d_in[11], (const float*)d_in[12], u1, u2);

    // pairwise MLP: f16 MFMA transposed chain (2048 blocks -> 8 waves/SIMD)
    mlp_mfma_kernel<<<2048, 256, 0, stream>>>(
        u1, u2, coo,
        (const float*)d_in[13], (const float*)d_in[14],
        (const float*)d_in[15], (const float*)d_in[16],
        (const float*)d_in[17], (const float*)d_in[18],
        (const float*)d_in[19], (const float*)d_in[20],
        (const float*)d_in[21], (const float*)d_in[22],
        (float*)d_out);
}

// Round 9
// 118.626 us; speedup vs baseline: 1.1421x; 1.1421x over previous
//
#include <hip/hip_runtime.h>
#include <cstdint>

#define N_RNA 4000
#define N_DIS 2000
#define NNODE 6016
#define NFDIM 128
#define RDIM 64
#define NE 300000
#define NET (NE + NNODE)
#define NPAIR 500000
#define NTILE (NPAIR / 16)  // 31250 exactly

typedef float vf4 __attribute__((ext_vector_type(4)));
typedef _Float16 f16x8 __attribute__((ext_vector_type(8)));
typedef _Float16 f16x2 __attribute__((ext_vector_type(2)));

union FragU {
    f16x8 f;
    f16x2 h[4];
    int   u[4];
    uint4 q;
};

__device__ __forceinline__ f16x2 pkrtz(float lo, float hi) {
    auto r = __builtin_amdgcn_cvt_pkrtz(lo, hi);
    return __builtin_bit_cast(f16x2, r);
}
__device__ __forceinline__ vf4 mfma16(const FragU& a, const FragU& b, vf4 c) {
    return __builtin_amdgcn_mfma_f32_16x16x32_f16(a.f, b.f, c, 0, 0, 0);
}
// packed f16: relu(a+b) on 2 lanes -> v_pk_add_f16 + v_pk_max_f16
__device__ __forceinline__ unsigned addrelu2(unsigned a, unsigned b) {
    f16x2 x = __builtin_bit_cast(f16x2, a) + __builtin_bit_cast(f16x2, b);
    f16x2 zz = {(_Float16)0.f, (_Float16)0.f};
    x = __builtin_elementwise_max(x, zz);
    return __builtin_bit_cast(unsigned, x);
}

// Rebuild B-fragment (next layer's a^T) from two C/D acc tiles, in-register.
__device__ __forceinline__ FragU trans32(vf4 a0, vf4 a1, int col, int g) {
    FragU w;
    w.h[0] = pkrtz(a0[0], a0[1]);
    w.h[1] = pkrtz(a0[2], a0[3]);
    w.h[2] = pkrtz(a1[0], a1[1]);
    w.h[3] = pkrtz(a1[2], a1[3]);
    int addrA = (col + 16 * ((2 * g) & 3)) * 4;
    int addrB = (col + 16 * ((2 * g + 1) & 3)) * 4;
    int t0a = __builtin_amdgcn_ds_bpermute(addrA, w.u[0]);
    int t1a = __builtin_amdgcn_ds_bpermute(addrA, w.u[1]);
    int t2a = __builtin_amdgcn_ds_bpermute(addrA, w.u[2]);
    int t3a = __builtin_amdgcn_ds_bpermute(addrA, w.u[3]);
    int t0b = __builtin_amdgcn_ds_bpermute(addrB, w.u[0]);
    int t1b = __builtin_amdgcn_ds_bpermute(addrB, w.u[1]);
    int t2b = __builtin_amdgcn_ds_bpermute(addrB, w.u[2]);
    int t3b = __builtin_amdgcn_ds_bpermute(addrB, w.u[3]);
    bool hi = g >= 2;
    FragU B;
    B.u[0] = hi ? t2a : t0a;
    B.u[1] = hi ? t3a : t1a;
    B.u[2] = hi ? t2b : t0b;
    B.u[3] = hi ? t3b : t1b;
    return B;
}

// 16-feature source (single acc tile) -> K=32 fragment zero-padded for k>=16.
__device__ __forceinline__ FragU trans16(vf4 a, int col, int g) {
    int w0, w1;
    {
        f16x2 p0 = pkrtz(a[0], a[1]);
        f16x2 p1 = pkrtz(a[2], a[3]);
        FragU tmp; tmp.h[0] = p0; tmp.h[1] = p1;
        w0 = tmp.u[0]; w1 = tmp.u[1];
    }
    int addrA = (col + 16 * ((2 * g) & 3)) * 4;
    int addrB = (col + 16 * ((2 * g + 1) & 3)) * 4;
    int j0 = __builtin_amdgcn_ds_bpermute(addrA, w0);
    int j1 = __builtin_amdgcn_ds_bpermute(addrA, w1);
    int j2 = __builtin_amdgcn_ds_bpermute(addrB, w0);
    int j3 = __builtin_amdgcn_ds_bpermute(addrB, w1);
    bool lo2 = g < 2;
    FragU B;
    B.u[0] = lo2 ? j0 : 0;
    B.u[1] = lo2 ? j1 : 0;
    B.u[2] = lo2 ? j2 : 0;
    B.u[3] = lo2 ? j3 : 0;
    return B;
}

// ---------------- CSR build ----------------
__global__ void init_cnt(int* __restrict__ cnt, int* __restrict__ cur) {
    int i = blockIdx.x * blockDim.x + threadIdx.x;
    if (i < NNODE) { cnt[i] = 0; cur[i] = 0; }
}

__global__ void count_edges(const int* __restrict__ adj, int* __restrict__ cnt) {
    int k = blockIdx.x * blockDim.x + threadIdx.x;
    if (k >= NET) return;
    int dst = (k < NE) ? adj[NE + k] : (k - NE);
    atomicAdd(&cnt[dst], 1);
}

__global__ __launch_bounds__(256) void scan_counts(const int* __restrict__ cnt,
                                                   int* __restrict__ offs) {
    __shared__ int part[256];
    const int C = 24;  // 256*24 = 6144 >= 6016
    int t = threadIdx.x;
    int base = t * C;
    int loc[C];
    int sum = 0;
#pragma unroll
    for (int i = 0; i < C; i++) {
        int idx = base + i;
        int v = (idx < NNODE) ? cnt[idx] : 0;
        loc[i] = sum;
        sum += v;
    }
    part[t] = sum;
    __syncthreads();
    for (int off = 1; off < 256; off <<= 1) {
        int v = (t >= off) ? part[t - off] : 0;
        __syncthreads();
        part[t] += v;
        __syncthreads();
    }
    int ebase = part[t] - sum;
#pragma unroll
    for (int i = 0; i < C; i++) {
        int idx = base + i;
        if (idx < NNODE) offs[idx] = ebase + loc[i];
    }
    if (t == 255) offs[NNODE] = part[255];
}

__global__ void fill_csr(const int* __restrict__ adj, const int* __restrict__ offs,
                         int* __restrict__ cur, int* __restrict__ srcs) {
    int k = blockIdx.x * blockDim.x + threadIdx.x;
    if (k >= NET) return;
    int src, dst;
    if (k < NE) { src = adj[k]; dst = adj[NE + k]; }
    else        { src = k - NE; dst = k - NE; }
    int pos = atomicAdd(&cur[dst], 1);
    srcs[offs[dst] + pos] = src;
}

// ---------------- GAT projection: 4 nodes per wave, W loaded once per 4 ----------------
template <int NF>
__global__ __launch_bounds__(64) void proj_kernel(const float* __restrict__ x,
                                                  const float* __restrict__ W,
                                                  const float* __restrict__ a_s,
                                                  const float* __restrict__ a_d,
                                                  float* __restrict__ h,
                                                  float* __restrict__ ssrc,
                                                  float* __restrict__ sdst) {
    __shared__ float xr[4][NF];
    int nb = blockIdx.x * 4;
    int t = threadIdx.x;
    for (int idx = t; idx < 4 * NF; idx += 64)
        xr[idx / NF][idx % NF] = x[(size_t)nb * NF + idx];
    __syncthreads();
    float a0 = 0.f, a1 = 0.f, a2 = 0.f, a3 = 0.f;
#pragma unroll 8
    for (int k = 0; k < NF; k++) {
        float wv = W[k * RDIM + t];
        a0 = fmaf(xr[0][k], wv, a0);
        a1 = fmaf(xr[1][k], wv, a1);
        a2 = fmaf(xr[2][k], wv, a2);
        a3 = fmaf(xr[3][k], wv, a3);
    }
    h[(size_t)(nb + 0) * RDIM + t] = a0;
    h[(size_t)(nb + 1) * RDIM + t] = a1;
    h[(size_t)(nb + 2) * RDIM + t] = a2;
    h[(size_t)(nb + 3) * RDIM + t] = a3;
    float asv = a_s[t], adv = a_d[t];
    float acc[4] = {a0, a1, a2, a3};
#pragma unroll
    for (int i = 0; i < 4; i++) {
        float vs = acc[i] * asv;
        float vd = acc[i] * adv;
#pragma unroll
        for (int off = 32; off; off >>= 1) {
            vs += __shfl_down(vs, off);
            vd += __shfl_down(vd, off);
        }
        if (t == 0) { ssrc[nb + i] = vs; sdst[nb + i] = vd; }
    }
}

// ---------------- GAT aggregation v2: 4 edge-groups x 16 lanes x float4 ----------------
__global__ __launch_bounds__(64) void agg_kernel(const float* __restrict__ h,
                                                 const float* __restrict__ ssrc,
                                                 const float* __restrict__ sdst,
                                                 const int* __restrict__ offs,
                                                 const int* __restrict__ srcs,
                                                 const float* __restrict__ bias,
                                                 float* __restrict__ out) {
    int node = blockIdx.x;
    int t = threadIdx.x;
    int beg = offs[node], end = offs[node + 1];
    float sd = sdst[node];
    float m = -1e30f;
    for (int i = beg + t; i < end; i += 64) {
        float v = ssrc[srcs[i]] + sd;
        v = v > 0.f ? v : 0.2f * v;
        m = fmaxf(m, v);
    }
#pragma unroll
    for (int off = 32; off; off >>= 1) m = fmaxf(m, __shfl_xor(m, off));
    int g = t >> 4, q = t & 15;
    float ax = 0.f, ay = 0.f, az = 0.f, aw = 0.f, den = 0.f;
    for (int i = beg + g; i < end; i += 4) {
        int s = srcs[i];
        float v = ssrc[s] + sd;
        v = v > 0.f ? v : 0.2f * v;
        float ex = __expf(v - m);
        den += ex;
        float4 hv = *(const float4*)(h + (size_t)s * 64 + q * 4);
        ax = fmaf(ex, hv.x, ax);
        ay = fmaf(ex, hv.y, ay);
        az = fmaf(ex, hv.z, az);
        aw = fmaf(ex, hv.w, aw);
    }
#pragma unroll
    for (int off = 16; off <= 32; off <<= 1) {
        ax += __shfl_xor(ax, off);
        ay += __shfl_xor(ay, off);
        az += __shfl_xor(az, off);
        aw += __shfl_xor(aw, off);
        den += __shfl_xor(den, off);
    }
    if (t < 16) {
        float inv = 1.f / den;
        float4 b4 = ((const float4*)bias)[q];
        float4 o;
        o.x = ax * inv + b4.x;
        o.y = ay * inv + b4.y;
        o.z = az * inv + b4.z;
        o.w = aw * inv + b4.w;
        *(float4*)(out + (size_t)node * 64 + q * 4) = o;
    }
}

// ---------------- pair-independent layer-1 precompute: 4 nodes/wave, f16 output ----------------
__global__ __launch_bounds__(64) void pair_pre_kernel(const float* __restrict__ h,
                                                      const float* __restrict__ w1,
                                                      const float* __restrict__ b1,
                                                      _Float16* __restrict__ u1h,
                                                      _Float16* __restrict__ u2h) {
    __shared__ float xr[4][64];
    int nb = blockIdx.x * 4;   // N_RNA=4000 divisible by 4: block never straddles types
    int t = threadIdx.x;
    for (int idx = t; idx < 256; idx += 64)
        xr[idx >> 6][idx & 63] = h[(size_t)nb * RDIM + idx];
    __syncthreads();
    bool rna = nb < N_RNA;
    const float* w = rna ? w1 : (w1 + 64 * 64);
    float bv = rna ? b1[t] : 0.f;
    float a0 = bv, a1 = bv, a2 = bv, a3 = bv;
#pragma unroll 8
    for (int k = 0; k < 64; k++) {
        float wv = w[k * 64 + t];
        a0 = fmaf(xr[0][k], wv, a0);
        a1 = fmaf(xr[1][k], wv, a1);
        a2 = fmaf(xr[2][k], wv, a2);
        a3 = fmaf(xr[3][k], wv, a3);
    }
    _Float16* dst = rna ? (u1h + (size_t)nb * 64) : (u2h + (size_t)(nb - N_RNA) * 64);
    dst[0 * 64 + t] = (_Float16)a0;
    dst[1 * 64 + t] = (_Float16)a1;
    dst[2 * 64 + t] = (_Float16)a2;
    dst[3 * 64 + t] = (_Float16)a3;
}

// ---------------- weight-fragment precompute (1 wave) ----------------
// gfrag layout: [group 0..7][lane 0..63] of uint4 (the lane's FragU dwords).
// groups: 0..3 = A2[t][kt] (t*2+kt), 4..5 = A3[t], 6 = A4, 7 = A5.
__global__ void prep_frags(const float* __restrict__ w2, const float* __restrict__ w3,
                           const float* __restrict__ w4, const float* __restrict__ w5,
                           uint4* __restrict__ gfrag) {
    int l = threadIdx.x;  // 0..63
    int col = l & 15, g = l >> 4;
    FragU F;
#pragma unroll
    for (int t = 0; t < 2; t++)
#pragma unroll
        for (int kt = 0; kt < 2; kt++) {
#pragma unroll
            for (int j = 0; j < 4; j++) {
                int k = kt * 32 + g * 8 + 2 * j;
                F.h[j] = pkrtz(w2[k * 32 + t * 16 + col], w2[(k + 1) * 32 + t * 16 + col]);
            }
            gfrag[(t * 2 + kt) * 64 + l] = F.q;
        }
#pragma unroll
    for (int t = 0; t < 2; t++) {
#pragma unroll
        for (int j = 0; j < 4; j++) {
            int k = g * 8 + 2 * j;
            F.h[j] = pkrtz(w3[k * 32 + t * 16 + col], w3[(k + 1) * 32 + t * 16 + col]);
        }
        gfrag[(4 + t) * 64 + l] = F.q;
    }
#pragma unroll
    for (int j = 0; j < 4; j++) {
        int k = g * 8 + 2 * j;
        F.h[j] = pkrtz(w4[k * 16 + col], w4[(k + 1) * 16 + col]);
    }
    gfrag[6 * 64 + l] = F.q;
#pragma unroll
    for (int j = 0; j < 4; j++) {
        int k = g * 8 + 2 * j;
        if (g < 2 && col < 8)
            F.h[j] = pkrtz(w5[k * 8 + col], w5[(k + 1) * 8 + col]);
        else
            F.u[j] = 0;
    }
    gfrag[7 * 64 + l] = F.q;
}

// ---------------- pairwise MLP: f16 MFMA chain, LDS-staged weight frags ----------------
__global__ __launch_bounds__(256, 4) void mlp_mfma_kernel(
    const _Float16* __restrict__ u1h, const _Float16* __restrict__ u2h,
    const int* __restrict__ coo, const uint4* __restrict__ gfrag,
    const float* __restrict__ b2, const float* __restrict__ b3,
    const float* __restrict__ b4, const float* __restrict__ b5,
    const float* __restrict__ w6, const float* __restrict__ b6,
    float* __restrict__ out) {
    __shared__ uint4 lfrag[8 * 64];
    int tid = threadIdx.x;
    lfrag[tid] = gfrag[tid];
    lfrag[tid + 256] = gfrag[tid + 256];
    __syncthreads();

    const int lane = tid & 63;
    const int col  = lane & 15;   // pair-in-tile (B/D col)
    const int g    = lane >> 4;   // k-group
    const int wid  = blockIdx.x * 4 + (tid >> 6);
    const int nwaves = gridDim.x * 4;

    // biases per lane: out-feature = t*16 + 4g + r
    float bias2[8], bias3[8], bias4[4], bias5[4], w6r[4];
#pragma unroll
    for (int t = 0; t < 2; t++)
#pragma unroll
        for (int r = 0; r < 4; r++) {
            bias2[t * 4 + r] = b2[t * 16 + g * 4 + r];
            bias3[t * 4 + r] = b3[t * 16 + g * 4 + r];
        }
#pragma unroll
    for (int r = 0; r < 4; r++) {
        bias4[r] = b4[g * 4 + r];
        bias5[r] = (g < 2) ? b5[g * 4 + r] : 0.f;
        w6r[r]   = (g < 2) ? w6[g * 4 + r] : 0.f;
    }
    float b6v = b6[0];
    const vf4 z = {0.f, 0.f, 0.f, 0.f};

    for (int tile = wid; tile < NTILE; tile += nwaves) {
        int p = tile * 16 + col;
        int2 rd = ((const int2*)coo)[p];
        const uint4* pr = (const uint4*)(u1h + (size_t)rd.x * 64);  // 8 x uint4 per row
        const uint4* pd = (const uint4*)(u2h + (size_t)rd.y * 64);
        // entry: 4 f16 gathers; B0 = relu(u1[g*8..]+u2[g*8..]), B1 = same for 32+
        uint4 r0 = pr[g], d0 = pd[g];
        uint4 r1 = pr[4 + g], d1 = pd[4 + g];
        FragU B0, B1;
        B0.u[0] = addrelu2(r0.x, d0.x);
        B0.u[1] = addrelu2(r0.y, d0.y);
        B0.u[2] = addrelu2(r0.z, d0.z);
        B0.u[3] = addrelu2(r0.w, d0.w);
        B1.u[0] = addrelu2(r1.x, d1.x);
        B1.u[1] = addrelu2(r1.y, d1.y);
        B1.u[2] = addrelu2(r1.z, d1.z);
        B1.u[3] = addrelu2(r1.w, d1.w);

        FragU A;
        // layer 2 (64 -> 32): 2 out-tiles x 2 k-tiles, frags from LDS
        A.q = lfrag[0 * 64 + lane];
        vf4 acc0 = mfma16(A, B0, z);
        A.q = lfrag[1 * 64 + lane];
        acc0 = mfma16(A, B1, acc0);
        A.q = lfrag[2 * 64 + lane];
        vf4 acc1 = mfma16(A, B0, z);
        A.q = lfrag[3 * 64 + lane];
        acc1 = mfma16(A, B1, acc1);
#pragma unroll
        for (int r = 0; r < 4; r++) {
            acc0[r] = fmaxf(acc0[r] + bias2[r], 0.f);
            acc1[r] = fmaxf(acc1[r] + bias2[4 + r], 0.f);
        }
        // layer 3 (32 -> 32)
        FragU Bx = trans32(acc0, acc1, col, g);
        A.q = lfrag[4 * 64 + lane];
        acc0 = mfma16(A, Bx, z);
        A.q = lfrag[5 * 64 + lane];
        acc1 = mfma16(A, Bx, z);
#pragma unroll
        for (int r = 0; r < 4; r++) {
            acc0[r] = fmaxf(acc0[r] + bias3[r], 0.f);
            acc1[r] = fmaxf(acc1[r] + bias3[4 + r], 0.f);
        }
        // layer 4 (32 -> 16)
        Bx = trans32(acc0, acc1, col, g);
        A.q = lfrag[6 * 64 + lane];
        vf4 a4 = mfma16(A, Bx, z);
#pragma unroll
        for (int r = 0; r < 4; r++) a4[r] = fmaxf(a4[r] + bias4[r], 0.f);
        // layer 5 (16 -> 8, padded to 16x32)
        Bx = trans16(a4, col, g);
        A.q = lfrag[7 * 64 + lane];
        vf4 a5 = mfma16(A, Bx, z);
        // layer 6 (8 -> 1) + sigmoid on VALU
        float part = 0.f;
#pragma unroll
        for (int r = 0; r < 4; r++)
            part = fmaf(fmaxf(a5[r] + bias5[r], 0.f), w6r[r], part);
        part += __shfl_xor(part, 16);
        float sig = 1.f / (1.f + __expf(-(part + b6v)));
        if (g == 0) out[tile * 16 + col] = sig;
    }
}

// ---------------- launch ----------------
extern "C" void kernel_launch(void* const* d_in, const int* in_sizes, int n_in,
                              void* d_out, int out_size, void* d_ws, size_t ws_size,
                              hipStream_t stream) {
    const float* x    = (const float*)d_in[0];
    const int*   adj  = (const int*)d_in[1];
    const int*   coo  = (const int*)d_in[2];
    const float* gw0  = (const float*)d_in[3];
    const float* gas0 = (const float*)d_in[4];
    const float* gad0 = (const float*)d_in[5];
    const float* gb0  = (const float*)d_in[6];
    const float* gw1  = (const float*)d_in[7];
    const float* gas1 = (const float*)d_in[8];
    const float* gad1 = (const float*)d_in[9];
    const float* gb1  = (const float*)d_in[10];

    char* ws = (char*)d_ws;
    size_t o = 0;
    auto take = [&](size_t bytes) -> void* {
        void* p = ws + o;
        o = (o + bytes + 255) & ~(size_t)255;
        return p;
    };
    float*     hP    = (float*)take((size_t)NNODE * RDIM * 4);
    float*     hO1   = (float*)take((size_t)NNODE * RDIM * 4);
    float*     hO2   = (float*)take((size_t)NNODE * RDIM * 4);
    _Float16*  u1h   = (_Float16*)take((size_t)N_RNA * 64 * 2);
    _Float16*  u2h   = (_Float16*)take((size_t)N_DIS * 64 * 2);
    uint4*     gfrag = (uint4*)take((size_t)8 * 64 * 16);
    float*     ssrc  = (float*)take((size_t)NNODE * 4);
    float*     sdst  = (float*)take((size_t)NNODE * 4);
    int*       offs  = (int*)take((size_t)(NNODE + 1) * 4);
    int*       cnt   = (int*)take((size_t)NNODE * 4);
    int*       cur   = (int*)take((size_t)NNODE * 4);
    int*       srcs  = (int*)take((size_t)NET * 4);

    init_cnt<<<(NNODE + 255) / 256, 256, 0, stream>>>(cnt, cur);
    count_edges<<<(NET + 255) / 256, 256, 0, stream>>>(adj, cnt);
    scan_counts<<<1, 256, 0, stream>>>(cnt, offs);
    fill_csr<<<(NET + 255) / 256, 256, 0, stream>>>(adj, offs, cur, srcs);

    // weight-fragment precompute (independent of GAT)
    prep_frags<<<1, 64, 0, stream>>>(
        (const float*)d_in[13], (const float*)d_in[15],
        (const float*)d_in[17], (const float*)d_in[19], gfrag);

    // GAT layer 1
    proj_kernel<NFDIM><<<NNODE / 4, 64, 0, stream>>>(x, gw0, gas0, gad0, hP, ssrc, sdst);
    agg_kernel<<<NNODE, 64, 0, stream>>>(hP, ssrc, sdst, offs, srcs, gb0, hO1);
    // GAT layer 2
    proj_kernel<RDIM><<<NNODE / 4, 64, 0, stream>>>(hO1, gw1, gas1, gad1, hP, ssrc, sdst);
    agg_kernel<<<NNODE, 64, 0, stream>>>(hP, ssrc, sdst, offs, srcs, gb1, hO2);

    // layer-1 precompute: u1 (rna nodes, +b1 folded), u2 (dis nodes), f16
    pair_pre_kernel<<<(N_RNA + N_DIS) / 4, 64, 0, stream>>>(
        hO2, (const float*)d_in[11], (const float*)d_in[12], u1h, u2h);

    // pairwise MLP
    mlp_mfma_kernel<<<1024, 256, 0, stream>>>(
        u1h, u2h, coo, gfrag,
        (const float*)d_in[14], (const float*)d_in[16],
        (const float*)d_in[18], (const float*)d_in[20],
        (const float*)d_in[21], (const float*)d_in[22],
        (float*)d_out);
}

// Round 10
// 103.366 us; speedup vs baseline: 1.3107x; 1.1476x over previous
//
#include <hip/hip_runtime.h>
#include <cstdint>

#define N_RNA 4000
#define N_DIS 2000
#define NNODE 6016
#define NFDIM 128
#define RDIM 64
#define NE 300000
#define NET (NE + NNODE)
#define NPAIR 500000
#define NTILE (NPAIR / 16)  // 31250 exactly

typedef float vf4 __attribute__((ext_vector_type(4)));
typedef _Float16 f16x8 __attribute__((ext_vector_type(8)));
typedef _Float16 f16x2 __attribute__((ext_vector_type(2)));

union FragU {
    f16x8 f;
    f16x2 h[4];
    int   u[4];
    uint4 q;
};

__device__ __forceinline__ f16x2 pkrtz(float lo, float hi) {
    auto r = __builtin_amdgcn_cvt_pkrtz(lo, hi);
    return __builtin_bit_cast(f16x2, r);
}
__device__ __forceinline__ vf4 mfma16(const FragU& a, const FragU& b, vf4 c) {
    return __builtin_amdgcn_mfma_f32_16x16x32_f16(a.f, b.f, c, 0, 0, 0);
}
// packed f16: relu(a+b) on 2 lanes -> v_pk_add_f16 + v_pk_max_f16
__device__ __forceinline__ unsigned addrelu2(unsigned a, unsigned b) {
    f16x2 x = __builtin_bit_cast(f16x2, a) + __builtin_bit_cast(f16x2, b);
    f16x2 zz = {(_Float16)0.f, (_Float16)0.f};
    x = __builtin_elementwise_max(x, zz);
    return __builtin_bit_cast(unsigned, x);
}

// Rebuild B-fragment (next layer's a^T) from two C/D acc tiles, in-register.
__device__ __forceinline__ FragU trans32(vf4 a0, vf4 a1, int col, int g) {
    FragU w;
    w.h[0] = pkrtz(a0[0], a0[1]);
    w.h[1] = pkrtz(a0[2], a0[3]);
    w.h[2] = pkrtz(a1[0], a1[1]);
    w.h[3] = pkrtz(a1[2], a1[3]);
    int addrA = (col + 16 * ((2 * g) & 3)) * 4;
    int addrB = (col + 16 * ((2 * g + 1) & 3)) * 4;
    int t0a = __builtin_amdgcn_ds_bpermute(addrA, w.u[0]);
    int t1a = __builtin_amdgcn_ds_bpermute(addrA, w.u[1]);
    int t2a = __builtin_amdgcn_ds_bpermute(addrA, w.u[2]);
    int t3a = __builtin_amdgcn_ds_bpermute(addrA, w.u[3]);
    int t0b = __builtin_amdgcn_ds_bpermute(addrB, w.u[0]);
    int t1b = __builtin_amdgcn_ds_bpermute(addrB, w.u[1]);
    int t2b = __builtin_amdgcn_ds_bpermute(addrB, w.u[2]);
    int t3b = __builtin_amdgcn_ds_bpermute(addrB, w.u[3]);
    bool hi = g >= 2;
    FragU B;
    B.u[0] = hi ? t2a : t0a;
    B.u[1] = hi ? t3a : t1a;
    B.u[2] = hi ? t2b : t0b;
    B.u[3] = hi ? t3b : t1b;
    return B;
}

// 16-feature source (single acc tile) -> K=32 fragment zero-padded for k>=16.
__device__ __forceinline__ FragU trans16(vf4 a, int col, int g) {
    int w0, w1;
    {
        f16x2 p0 = pkrtz(a[0], a[1]);
        f16x2 p1 = pkrtz(a[2], a[3]);
        FragU tmp; tmp.h[0] = p0; tmp.h[1] = p1;
        w0 = tmp.u[0]; w1 = tmp.u[1];
    }
    int addrA = (col + 16 * ((2 * g) & 3)) * 4;
    int addrB = (col + 16 * ((2 * g + 1) & 3)) * 4;
    int j0 = __builtin_amdgcn_ds_bpermute(addrA, w0);
    int j1 = __builtin_amdgcn_ds_bpermute(addrA, w1);
    int j2 = __builtin_amdgcn_ds_bpermute(addrB, w0);
    int j3 = __builtin_amdgcn_ds_bpermute(addrB, w1);
    bool lo2 = g < 2;
    FragU B;
    B.u[0] = lo2 ? j0 : 0;
    B.u[1] = lo2 ? j1 : 0;
    B.u[2] = lo2 ? j2 : 0;
    B.u[3] = lo2 ? j3 : 0;
    return B;
}

// ---------------- setup: zero counters + weight-fragment precompute ----------------
__global__ void setup_kernel(int* __restrict__ cnt, int* __restrict__ cur,
                             const float* __restrict__ w2, const float* __restrict__ w3,
                             const float* __restrict__ w4, const float* __restrict__ w5,
                             uint4* __restrict__ gfrag) {
    int i = blockIdx.x * blockDim.x + threadIdx.x;
    if (i < NNODE) { cnt[i] = 0; cur[i] = 0; }
    if (blockIdx.x == 0 && threadIdx.x < 64) {
        int l = threadIdx.x;
        int col = l & 15, g = l >> 4;
        FragU F;
#pragma unroll
        for (int t = 0; t < 2; t++)
#pragma unroll
            for (int kt = 0; kt < 2; kt++) {
#pragma unroll
                for (int j = 0; j < 4; j++) {
                    int k = kt * 32 + g * 8 + 2 * j;
                    F.h[j] = pkrtz(w2[k * 32 + t * 16 + col], w2[(k + 1) * 32 + t * 16 + col]);
                }
                gfrag[(t * 2 + kt) * 64 + l] = F.q;
            }
#pragma unroll
        for (int t = 0; t < 2; t++) {
#pragma unroll
            for (int j = 0; j < 4; j++) {
                int k = g * 8 + 2 * j;
                F.h[j] = pkrtz(w3[k * 32 + t * 16 + col], w3[(k + 1) * 32 + t * 16 + col]);
            }
            gfrag[(4 + t) * 64 + l] = F.q;
        }
#pragma unroll
        for (int j = 0; j < 4; j++) {
            int k = g * 8 + 2 * j;
            F.h[j] = pkrtz(w4[k * 16 + col], w4[(k + 1) * 16 + col]);
        }
        gfrag[6 * 64 + l] = F.q;
#pragma unroll
        for (int j = 0; j < 4; j++) {
            int k = g * 8 + 2 * j;
            if (g < 2 && col < 8)
                F.h[j] = pkrtz(w5[k * 8 + col], w5[(k + 1) * 8 + col]);
            else
                F.u[j] = 0;
        }
        gfrag[7 * 64 + l] = F.q;
    }
}

__global__ void count_edges(const int* __restrict__ adj, int* __restrict__ cnt) {
    int k = blockIdx.x * blockDim.x + threadIdx.x;
    if (k >= NET) return;
    int dst = (k < NE) ? adj[NE + k] : (k - NE);
    atomicAdd(&cnt[dst], 1);
}

__global__ __launch_bounds__(256) void scan_counts(const int* __restrict__ cnt,
                                                   int* __restrict__ offs) {
    __shared__ int part[256];
    const int C = 24;  // 256*24 = 6144 >= 6016
    int t = threadIdx.x;
    int base = t * C;
    int loc[C];
    int sum = 0;
#pragma unroll
    for (int i = 0; i < C; i++) {
        int idx = base + i;
        int v = (idx < NNODE) ? cnt[idx] : 0;
        loc[i] = sum;
        sum += v;
    }
    part[t] = sum;
    __syncthreads();
    for (int off = 1; off < 256; off <<= 1) {
        int v = (t >= off) ? part[t - off] : 0;
        __syncthreads();
        part[t] += v;
        __syncthreads();
    }
    int ebase = part[t] - sum;
#pragma unroll
    for (int i = 0; i < C; i++) {
        int idx = base + i;
        if (idx < NNODE) offs[idx] = ebase + loc[i];
    }
    if (t == 255) offs[NNODE] = part[255];
}

__global__ void fill_csr(const int* __restrict__ adj, const int* __restrict__ offs,
                         int* __restrict__ cur, int* __restrict__ srcs) {
    int k = blockIdx.x * blockDim.x + threadIdx.x;
    if (k >= NET) return;
    int src, dst;
    if (k < NE) { src = adj[k]; dst = adj[NE + k]; }
    else        { src = k - NE; dst = k - NE; }
    int pos = atomicAdd(&cur[dst], 1);
    srcs[offs[dst] + pos] = src;
}

// ---------------- GAT layer-1 projection: 4 nodes per wave ----------------
template <int NF>
__global__ __launch_bounds__(64) void proj_kernel(const float* __restrict__ x,
                                                  const float* __restrict__ W,
                                                  const float* __restrict__ a_s,
                                                  const float* __restrict__ a_d,
                                                  float* __restrict__ h,
                                                  float* __restrict__ ssrc,
                                                  float* __restrict__ sdst) {
    __shared__ float xr[4][NF];
    int nb = blockIdx.x * 4;
    int t = threadIdx.x;
    for (int idx = t; idx < 4 * NF; idx += 64)
        xr[idx / NF][idx % NF] = x[(size_t)nb * NF + idx];
    __syncthreads();
    float a0 = 0.f, a1 = 0.f, a2 = 0.f, a3 = 0.f;
#pragma unroll 8
    for (int k = 0; k < NF; k++) {
        float wv = W[k * RDIM + t];
        a0 = fmaf(xr[0][k], wv, a0);
        a1 = fmaf(xr[1][k], wv, a1);
        a2 = fmaf(xr[2][k], wv, a2);
        a3 = fmaf(xr[3][k], wv, a3);
    }
    h[(size_t)(nb + 0) * RDIM + t] = a0;
    h[(size_t)(nb + 1) * RDIM + t] = a1;
    h[(size_t)(nb + 2) * RDIM + t] = a2;
    h[(size_t)(nb + 3) * RDIM + t] = a3;
    float asv = a_s[t], adv = a_d[t];
    float acc[4] = {a0, a1, a2, a3};
#pragma unroll
    for (int i = 0; i < 4; i++) {
        float vs = acc[i] * asv;
        float vd = acc[i] * adv;
#pragma unroll
        for (int off = 32; off; off >>= 1) {
            vs += __shfl_down(vs, off);
            vd += __shfl_down(vd, off);
        }
        if (t == 0) { ssrc[nb + i] = vs; sdst[nb + i] = vd; }
    }
}

// Shared edge-softmax-aggregate body (no max pass; 8 edge groups x 8 lanes x 8 floats).
// After this, lanes 0..7 hold (in A0,A1) the aggregated features [t*8, t*8+8) and den.
#define AGG_BODY(H, SS, SD)                                                 \
    int beg = offs[node], end = offs[node + 1];                             \
    float sd = (SD)[node];                                                  \
    int g8 = t >> 3, q8 = t & 7;                                            \
    float4 A0 = {0.f, 0.f, 0.f, 0.f}, A1 = {0.f, 0.f, 0.f, 0.f};            \
    float den = 0.f;                                                        \
    for (int i = beg + g8; i < end; i += 8) {                               \
        int s = srcs[i];                                                    \
        float v = (SS)[s] + sd;                                             \
        v = v > 0.f ? v : 0.2f * v;                                         \
        float ex = __expf(v);                                               \
        den += ex;                                                          \
        const float4* hp = (const float4*)((H) + (size_t)s * 64 + q8 * 8);  \
        float4 h0 = hp[0], h1 = hp[1];                                      \
        A0.x = fmaf(ex, h0.x, A0.x); A0.y = fmaf(ex, h0.y, A0.y);           \
        A0.z = fmaf(ex, h0.z, A0.z); A0.w = fmaf(ex, h0.w, A0.w);           \
        A1.x = fmaf(ex, h1.x, A1.x); A1.y = fmaf(ex, h1.y, A1.y);           \
        A1.z = fmaf(ex, h1.z, A1.z); A1.w = fmaf(ex, h1.w, A1.w);           \
    }                                                                       \
    _Pragma("unroll")                                                       \
    for (int off = 8; off <= 32; off <<= 1) {                               \
        A0.x += __shfl_xor(A0.x, off); A0.y += __shfl_xor(A0.y, off);       \
        A0.z += __shfl_xor(A0.z, off); A0.w += __shfl_xor(A0.w, off);       \
        A1.x += __shfl_xor(A1.x, off); A1.y += __shfl_xor(A1.y, off);       \
        A1.z += __shfl_xor(A1.z, off); A1.w += __shfl_xor(A1.w, off);       \
        den += __shfl_xor(den, off);                                        \
    }

// ---------------- GAT layer 1 agg + fused layer-2 projection ----------------
__global__ __launch_bounds__(64) void agg_proj_kernel(
    const float* __restrict__ h, const float* __restrict__ ssrc, const float* __restrict__ sdst,
    const int* __restrict__ offs, const int* __restrict__ srcs,
    const float* __restrict__ bias,  // gb0
    const float* __restrict__ W,     // gw1 (64x64)
    const float* __restrict__ a_s, const float* __restrict__ a_d,  // gas1, gad1
    float* __restrict__ h2, float* __restrict__ ssrc2, float* __restrict__ sdst2) {
    int node = blockIdx.x;
    int t = threadIdx.x;
    AGG_BODY(h, ssrc, sdst)
    __shared__ float sm[64];
    if (t < 8) {
        float inv = 1.f / den;
        sm[8 * t + 0] = A0.x * inv + bias[8 * t + 0];
        sm[8 * t + 1] = A0.y * inv + bias[8 * t + 1];
        sm[8 * t + 2] = A0.z * inv + bias[8 * t + 2];
        sm[8 * t + 3] = A0.w * inv + bias[8 * t + 3];
        sm[8 * t + 4] = A1.x * inv + bias[8 * t + 4];
        sm[8 * t + 5] = A1.y * inv + bias[8 * t + 5];
        sm[8 * t + 6] = A1.z * inv + bias[8 * t + 6];
        sm[8 * t + 7] = A1.w * inv + bias[8 * t + 7];
    }
    __syncthreads();
    float hv = 0.f;
#pragma unroll 8
    for (int k = 0; k < 64; k++) hv = fmaf(sm[k], W[k * 64 + t], hv);
    h2[(size_t)node * 64 + t] = hv;
    float vs = hv * a_s[t];
    float vd = hv * a_d[t];
#pragma unroll
    for (int off = 32; off; off >>= 1) {
        vs += __shfl_down(vs, off);
        vd += __shfl_down(vd, off);
    }
    if (t == 0) { ssrc2[node] = vs; sdst2[node] = vd; }
}

// ---------------- GAT layer 2 agg + fused MLP layer-1 precompute (grid 6000) --------
__global__ __launch_bounds__(64) void agg_pre_kernel(
    const float* __restrict__ h, const float* __restrict__ ssrc, const float* __restrict__ sdst,
    const int* __restrict__ offs, const int* __restrict__ srcs,
    const float* __restrict__ bias,  // gb1
    const float* __restrict__ w1, const float* __restrict__ b1,
    _Float16* __restrict__ u1h, _Float16* __restrict__ u2h) {
    int node = blockIdx.x;  // 0..5999 (global nodes not needed downstream)
    int t = threadIdx.x;
    AGG_BODY(h, ssrc, sdst)
    __shared__ float sm[64];
    if (t < 8) {
        float inv = 1.f / den;
        sm[8 * t + 0] = A0.x * inv + bias[8 * t + 0];
        sm[8 * t + 1] = A0.y * inv + bias[8 * t + 1];
        sm[8 * t + 2] = A0.z * inv + bias[8 * t + 2];
        sm[8 * t + 3] = A0.w * inv + bias[8 * t + 3];
        sm[8 * t + 4] = A1.x * inv + bias[8 * t + 4];
        sm[8 * t + 5] = A1.y * inv + bias[8 * t + 5];
        sm[8 * t + 6] = A1.z * inv + bias[8 * t + 6];
        sm[8 * t + 7] = A1.w * inv + bias[8 * t + 7];
    }
    __syncthreads();
    bool rna = node < N_RNA;
    const float* w = rna ? w1 : (w1 + 64 * 64);
    float uk = rna ? b1[t] : 0.f;
#pragma unroll 8
    for (int k = 0; k < 64; k++) uk = fmaf(sm[k], w[k * 64 + t], uk);
    _Float16* dst = rna ? (u1h + (size_t)node * 64) : (u2h + (size_t)(node - N_RNA) * 64);
    dst[t] = (_Float16)uk;
}

// ---------------- pairwise MLP: f16 MFMA chain, LDS-staged weight frags ----------------
__global__ __launch_bounds__(256, 4) void mlp_mfma_kernel(
    const _Float16* __restrict__ u1h, const _Float16* __restrict__ u2h,
    const int* __restrict__ coo, const uint4* __restrict__ gfrag,
    const float* __restrict__ b2, const float* __restrict__ b3,
    const float* __restrict__ b4, const float* __restrict__ b5,
    const float* __restrict__ w6, const float* __restrict__ b6,
    float* __restrict__ out) {
    __shared__ uint4 lfrag[8 * 64];
    int tid = threadIdx.x;
    lfrag[tid] = gfrag[tid];
    lfrag[tid + 256] = gfrag[tid + 256];
    __syncthreads();

    const int lane = tid & 63;
    const int col  = lane & 15;   // pair-in-tile (B/D col)
    const int g    = lane >> 4;   // k-group
    const int wid  = blockIdx.x * 4 + (tid >> 6);
    const int nwaves = gridDim.x * 4;

    // biases per lane: out-feature = t*16 + 4g + r
    float bias2[8], bias3[8], bias4[4], bias5[4], w6r[4];
#pragma unroll
    for (int t = 0; t < 2; t++)
#pragma unroll
        for (int r = 0; r < 4; r++) {
            bias2[t * 4 + r] = b2[t * 16 + g * 4 + r];
            bias3[t * 4 + r] = b3[t * 16 + g * 4 + r];
        }
#pragma unroll
    for (int r = 0; r < 4; r++) {
        bias4[r] = b4[g * 4 + r];
        bias5[r] = (g < 2) ? b5[g * 4 + r] : 0.f;
        w6r[r]   = (g < 2) ? w6[g * 4 + r] : 0.f;
    }
    float b6v = b6[0];
    const vf4 z = {0.f, 0.f, 0.f, 0.f};

    for (int tile = wid; tile < NTILE; tile += nwaves) {
        int p = tile * 16 + col;
        int2 rd = ((const int2*)coo)[p];
        const uint4* pr = (const uint4*)(u1h + (size_t)rd.x * 64);  // 8 x uint4 per row
        const uint4* pd = (const uint4*)(u2h + (size_t)rd.y * 64);
        uint4 r0 = pr[g], d0 = pd[g];
        uint4 r1 = pr[4 + g], d1 = pd[4 + g];
        FragU B0, B1;
        B0.u[0] = addrelu2(r0.x, d0.x);
        B0.u[1] = addrelu2(r0.y, d0.y);
        B0.u[2] = addrelu2(r0.z, d0.z);
        B0.u[3] = addrelu2(r0.w, d0.w);
        B1.u[0] = addrelu2(r1.x, d1.x);
        B1.u[1] = addrelu2(r1.y, d1.y);
        B1.u[2] = addrelu2(r1.z, d1.z);
        B1.u[3] = addrelu2(r1.w, d1.w);

        FragU A;
        // layer 2 (64 -> 32): 2 out-tiles x 2 k-tiles, frags from LDS
        A.q = lfrag[0 * 64 + lane];
        vf4 acc0 = mfma16(A, B0, z);
        A.q = lfrag[1 * 64 + lane];
        acc0 = mfma16(A, B1, acc0);
        A.q = lfrag[2 * 64 + lane];
        vf4 acc1 = mfma16(A, B0, z);
        A.q = lfrag[3 * 64 + lane];
        acc1 = mfma16(A, B1, acc1);
#pragma unroll
        for (int r = 0; r < 4; r++) {
            acc0[r] = fmaxf(acc0[r] + bias2[r], 0.f);
            acc1[r] = fmaxf(acc1[r] + bias2[4 + r], 0.f);
        }
        // layer 3 (32 -> 32)
        FragU Bx = trans32(acc0, acc1, col, g);
        A.q = lfrag[4 * 64 + lane];
        acc0 = mfma16(A, Bx, z);
        A.q = lfrag[5 * 64 + lane];
        acc1 = mfma16(A, Bx, z);
#pragma unroll
        for (int r = 0; r < 4; r++) {
            acc0[r] = fmaxf(acc0[r] + bias3[r], 0.f);
            acc1[r] = fmaxf(acc1[r] + bias3[4 + r], 0.f);
        }
        // layer 4 (32 -> 16)
        Bx = trans32(acc0, acc1, col, g);
        A.q = lfrag[6 * 64 + lane];
        vf4 a4 = mfma16(A, Bx, z);
#pragma unroll
        for (int r = 0; r < 4; r++) a4[r] = fmaxf(a4[r] + bias4[r], 0.f);
        // layer 5 (16 -> 8, padded to 16x32)
        Bx = trans16(a4, col, g);
        A.q = lfrag[7 * 64 + lane];
        vf4 a5 = mfma16(A, Bx, z);
        // layer 6 (8 -> 1) + sigmoid on VALU
        float part = 0.f;
#pragma unroll
        for (int r = 0; r < 4; r++)
            part = fmaf(fmaxf(a5[r] + bias5[r], 0.f), w6r[r], part);
        part += __shfl_xor(part, 16);
        float sig = 1.f / (1.f + __expf(-(part + b6v)));
        if (g == 0) out[tile * 16 + col] = sig;
    }
}

// ---------------- launch ----------------
extern "C" void kernel_launch(void* const* d_in, const int* in_sizes, int n_in,
                              void* d_out, int out_size, void* d_ws, size_t ws_size,
                              hipStream_t stream) {
    const float* x    = (const float*)d_in[0];
    const int*   adj  = (const int*)d_in[1];
    const int*   coo  = (const int*)d_in[2];
    const float* gw0  = (const float*)d_in[3];
    const float* gas0 = (const float*)d_in[4];
    const float* gad0 = (const float*)d_in[5];
    const float* gb0  = (const float*)d_in[6];
    const float* gw1  = (const float*)d_in[7];
    const float* gas1 = (const float*)d_in[8];
    const float* gad1 = (const float*)d_in[9];
    const float* gb1  = (const float*)d_in[10];

    char* ws = (char*)d_ws;
    size_t o = 0;
    auto take = [&](size_t bytes) -> void* {
        void* p = ws + o;
        o = (o + bytes + 255) & ~(size_t)255;
        return p;
    };
    float*     hP    = (float*)take((size_t)NNODE * RDIM * 4);   // layer-1 projected
    float*     hP2   = (float*)take((size_t)NNODE * RDIM * 4);   // layer-2 projected
    _Float16*  u1h   = (_Float16*)take((size_t)N_RNA * 64 * 2);
    _Float16*  u2h   = (_Float16*)take((size_t)N_DIS * 64 * 2);
    uint4*     gfrag = (uint4*)take((size_t)8 * 64 * 16);
    float*     ssrc  = (float*)take((size_t)NNODE * 4);
    float*     sdst  = (float*)take((size_t)NNODE * 4);
    float*     ssrc2 = (float*)take((size_t)NNODE * 4);
    float*     sdst2 = (float*)take((size_t)NNODE * 4);
    int*       offs  = (int*)take((size_t)(NNODE + 1) * 4);
    int*       cnt   = (int*)take((size_t)NNODE * 4);
    int*       cur   = (int*)take((size_t)NNODE * 4);
    int*       srcs  = (int*)take((size_t)NET * 4);

    setup_kernel<<<(NNODE + 255) / 256, 256, 0, stream>>>(
        cnt, cur,
        (const float*)d_in[13], (const float*)d_in[15],
        (const float*)d_in[17], (const float*)d_in[19], gfrag);
    count_edges<<<(NET + 255) / 256, 256, 0, stream>>>(adj, cnt);
    scan_counts<<<1, 256, 0, stream>>>(cnt, offs);
    fill_csr<<<(NET + 255) / 256, 256, 0, stream>>>(adj, offs, cur, srcs);

    // GAT layer 1 projection
    proj_kernel<NFDIM><<<NNODE / 4, 64, 0, stream>>>(x, gw0, gas0, gad0, hP, ssrc, sdst);
    // layer-1 aggregate + fused layer-2 projection + scores
    agg_proj_kernel<<<NNODE, 64, 0, stream>>>(hP, ssrc, sdst, offs, srcs, gb0,
                                              gw1, gas1, gad1, hP2, ssrc2, sdst2);
    // layer-2 aggregate + fused MLP layer-1 precompute (f16 u-rows)
    agg_pre_kernel<<<N_RNA + N_DIS, 64, 0, stream>>>(
        hP2, ssrc2, sdst2, offs, srcs, gb1,
        (const float*)d_in[11], (const float*)d_in[12], u1h, u2h);

    // pairwise MLP
    mlp_mfma_kernel<<<1024, 256, 0, stream>>>(
        u1h, u2h, coo, gfrag,
        (const float*)d_in[14], (const float*)d_in[16],
        (const float*)d_in[18], (const float*)d_in[20],
        (const float*)d_in[21], (const float*)d_in[22],
        (float*)d_out);
}